// Round 15
// baseline (192.441 us; speedup 1.0000x reference)
//
#include <hip/hip_runtime.h>
#include <cstdint>
#include <cstddef>

typedef __attribute__((ext_vector_type(8))) short bf16x8;
typedef __attribute__((ext_vector_type(4))) float f32x4;
typedef __attribute__((ext_vector_type(16))) float f32x16;
typedef __attribute__((ext_vector_type(4))) unsigned int u32x4;

#define B_ 4
#define T_ 2048
#define DM 1024
#define NH 16
#define HD 64

static __device__ __forceinline__ unsigned short f2bf(float f) {
  union { float f; unsigned int u; } v; v.f = f;
  unsigned int r = v.u + 0x7FFFu + ((v.u >> 16) & 1u);
  return (unsigned short)(r >> 16);
}
static __device__ __forceinline__ float exp2_fast(float x) {
  float r;
  asm volatile("v_exp_f32 %0, %1" : "=v"(r) : "v"(x));
  return r;
}
static __device__ __forceinline__ unsigned int cvt_pk_bf16(float a, float b) {
  unsigned int r;
  asm("v_cvt_pk_bf16_f32 %0, %1, %2" : "=v"(r) : "v"(a), "v"(b));
  return r;
}

static __device__ __forceinline__ void gll16(const void* g, void* l) {
  __builtin_amdgcn_global_load_lds(
      (const __attribute__((address_space(1))) void*)g,
      (__attribute__((address_space(3))) void*)l, 16, 0, 0);
}

#define BARRIER() do { asm volatile("" ::: "memory"); __builtin_amdgcn_s_barrier(); asm volatile("" ::: "memory"); } while (0)
#define WAITV0() asm volatile("s_waitcnt vmcnt(0)" ::: "memory")

// ---------------- merged prep: cast x->bf16 + transpose both weights --------
__global__ __launch_bounds__(256) void prep_kernel(
    const float* __restrict__ x, unsigned short* __restrict__ x16,
    const float* __restrict__ w_qkv, unsigned short* __restrict__ wqkvT,
    const float* __restrict__ w_proj, unsigned short* __restrict__ wprojT) {
  __shared__ unsigned short tile[32][33];
  const int bid = blockIdx.x;
  const int tid = threadIdx.x;
  if (bid < 2048) {
    const int n8 = (B_ * T_ * DM) / 8;  // 1048576
    for (int i = bid * 256 + tid; i < n8; i += 2048 * 256) {
      const float4* p = (const float4*)(x + (size_t)i * 8);
      float4 a = p[0], b = p[1];
      u32x4 o;
      o[0] = cvt_pk_bf16(a.x, a.y);
      o[1] = cvt_pk_bf16(a.z, a.w);
      o[2] = cvt_pk_bf16(b.x, b.y);
      o[3] = cvt_pk_bf16(b.z, b.w);
      *(u32x4*)(x16 + (size_t)i * 8) = o;
    }
    return;
  }
  const float* in;
  unsigned short* out;
  int R, C, bx, by;
  if (bid < 5120) {
    const int b2 = bid - 2048;  // [0,3072)
    in = w_qkv; out = wqkvT; R = 1024; C = 3072;
    bx = b2 % 96; by = b2 / 96;
  } else {
    const int b2 = bid - 5120;  // [0,1024)
    in = w_proj; out = wprojT; R = 1024; C = 1024;
    bx = b2 % 32; by = b2 / 32;
  }
  const int c0 = bx * 32, r0 = by * 32;
  const int tx = tid & 31, ty = tid >> 5;
#pragma unroll
  for (int j = 0; j < 32; j += 8) {
    float v = in[(size_t)(r0 + ty + j) * C + c0 + tx];
    tile[tx][ty + j] = f2bf(v);
  }
  __syncthreads();
#pragma unroll
  for (int j = 0; j < 32; j += 8) {
    out[(size_t)(c0 + ty + j) * R + r0 + tx] = tile[ty + j][tx];
  }
}

// ---------------- GEMM core v2 (2-phase counted-vmcnt dbuf; proj only) ------
#define GEMM_MAIN2(As, Bs, Agl, Bgl, acc)                                    \
  {                                                                          \
    const char* gA = (const char*)(Agl) +                                    \
                     (size_t)(m0 + (tid >> 3)) * 2048 +                      \
                     (((tid & 7) ^ ((tid >> 3) & 7)) << 4);                  \
    const char* gB = (const char*)(Bgl) +                                    \
                     (size_t)(n0 + (tid >> 3)) * 2048 +                      \
                     (((tid & 7) ^ ((tid >> 3) & 7)) << 4);                  \
    _Pragma("unroll") for (int i = 0; i < 4; i++) {                          \
      gll16(gA + (size_t)i * 65536, (char*)(As) + i * 4096 + w * 1024);      \
      gll16(gB + (size_t)i * 65536, (char*)(Bs) + i * 4096 + w * 1024);      \
    }                                                                        \
    for (int t = 0; t < 16; t++) {                                           \
      const int cur = (t & 1) << 14;                                         \
      if (t < 15) {                                                          \
        const int nxt = ((t + 1) & 1) << 14;                                 \
        const int k0 = (t + 1) * 128;                                        \
        _Pragma("unroll") for (int i = 0; i < 4; i++) {                      \
          gll16(gA + (size_t)i * 65536 + k0,                                 \
                (char*)(As) + nxt + i * 4096 + w * 1024);                    \
          gll16(gB + (size_t)i * 65536 + k0,                                 \
                (char*)(Bs) + nxt + i * 4096 + w * 1024);                    \
        }                                                                    \
        asm volatile("s_waitcnt vmcnt(8)" ::: "memory");                     \
      } else {                                                               \
        asm volatile("s_waitcnt vmcnt(0)" ::: "memory");                     \
      }                                                                      \
      BARRIER();                                                             \
      _Pragma("unroll") for (int kk = 0; kk < 2; kk++) {                     \
        bf16x8 af[4], bfr[4];                                                \
        const int ko = (kk * 64 + lg * 16) ^ ((lr & 7) << 4);                \
        _Pragma("unroll") for (int mi = 0; mi < 4; mi++)                     \
            af[mi] = *(const bf16x8*)((const char*)(As) + cur +              \
                                      (wr * 64 + mi * 16 + lr) * 128 + ko);  \
        _Pragma("unroll") for (int ni = 0; ni < 4; ni++)                     \
            bfr[ni] = *(const bf16x8*)((const char*)(Bs) + cur +             \
                                       (wc * 64 + ni * 16 + lr) * 128 + ko); \
        _Pragma("unroll") for (int mi = 0; mi < 4; mi++)                     \
            _Pragma("unroll") for (int ni = 0; ni < 4; ni++)                 \
                acc[mi][ni] = __builtin_amdgcn_mfma_f32_16x16x32_bf16(       \
                    af[mi], bfr[ni], acc[mi][ni], 0, 0, 0);                  \
      }                                                                      \
      BARRIER();                                                             \
    }                                                                        \
  }

// ---------------- QKV GEMM v3: 256x256 tile, 4-phase counted-vmcnt pipeline -
// 384 blocks x 512 thr (8 waves, 2Mx4N; per-wave C = 128x64). LDS 128KB:
// A[2][256x64], B[2][256x64], rows 128B, XOR-swizzled (proven involution).
// Tile t+1 staged as 4 x 16KB pieces, one per phase, 2 gll16/thread each:
//   piece0 = A-even (rows {0-63,128-191})   -> needed at p0 (mh=0)
//   piece1 = B-nh0  (rows {0-31,64-95,128-159,192-223}) -> p0 (nh=0)
//   piece2 = A-odd  (rows {64-127,192-255}) -> p1 (mh=1)
//   piece3 = B-nh1  (rows +32 of piece1)    -> p2 (nh=1)
// Snake phases (mh,nh) = (0,0),(1,0),(1,1),(0,1) reuse B across p0/p1 and
// A across p1/p2. Steady-state ledger (2 loads/phase/wave): after issuing
// phase p's stage, outstanding = 8+2; vmcnt(6) drains exactly the 2-per-phase
// pieces aged >=3 phases = the pieces phase p consumes. Last iter: 4/2/0.
// One publish barrier per phase; one end-of-iter barrier covers the WAR on
// the buffer being restaged next iteration.
__global__ __launch_bounds__(512, 2) void gemm_qkv(
    const unsigned short* __restrict__ A, const unsigned short* __restrict__ Bt,
    const float* __restrict__ cosT, const float* __restrict__ sinT,
    unsigned short* __restrict__ Qo, unsigned short* __restrict__ Ko,
    unsigned short* __restrict__ VTo) {
  __shared__ __align__(16) char lds[131072];
  const int bid = blockIdx.x;
  const int xcd = bid & 7;
  const int cc = bid >> 3;  // [0,48)
  const int m0 = (xcd * 4 + (cc & 3)) * 256;
  const int n0 = (cc >> 2) * 256;
  const int tid = threadIdx.x;
  const int w = tid >> 6, l = tid & 63;
  const int wr = w >> 2, wc = w & 3;
  const int lr = l & 15, lg = l >> 4;

  // staging precompute (per-lane global src; wave-uniform LDS base: the row
  // maps are slope-1 over each wave's 8-row window, so dest = base + lane*16)
  const char* gsrc[4][2];
  int ldso[4][2];
  {
    const int cb = tid & 7;
#pragma unroll
    for (int i = 0; i < 2; i++) {
      const int rp = (tid + i * 512) >> 3;  // [0,128)
      const int rAe = rp + (rp & 64);
      const int rBn0 = ((rp >> 5) << 6) + (rp & 31);
      const int rAo = rp + 64 + (rp & 64);
      const int rBn1 = rBn0 + 32;
      gsrc[0][i] = (const char*)A + (size_t)(m0 + rAe) * 2048 + ((cb ^ (rAe & 7)) << 4);
      gsrc[1][i] = (const char*)Bt + (size_t)(n0 + rBn0) * 2048 + ((cb ^ (rBn0 & 7)) << 4);
      gsrc[2][i] = (const char*)A + (size_t)(m0 + rAo) * 2048 + ((cb ^ (rAo & 7)) << 4);
      gsrc[3][i] = (const char*)Bt + (size_t)(n0 + rBn1) * 2048 + ((cb ^ (rBn1 & 7)) << 4);
      const int rp0 = w * 8 + i * 64;  // wave window start
      const int fAe = rp0 + (rp0 & 64);
      const int fBn0 = ((rp0 >> 5) << 6) + (rp0 & 31);
      const int fAo = rp0 + 64 + (rp0 & 64);
      const int fBn1 = fBn0 + 32;
      ldso[0][i] = fAe * 128;
      ldso[1][i] = 65536 + fBn0 * 128;
      ldso[2][i] = fAo * 128;
      ldso[3][i] = 65536 + fBn1 * 128;
    }
  }

#define STG(q, i, kb, nb) gll16(gsrc[q][i] + (kb), lds + ldso[q][i] + (nb) * 32768)

  f32x4 acc[8][4];
#pragma unroll
  for (int i = 0; i < 8; i++)
#pragma unroll
    for (int j = 0; j < 4; j++) acc[i][j] = (f32x4)0.f;

  // prologue: tile 0 -> buf 0, fully drained
#pragma unroll
  for (int q = 0; q < 4; q++) {
    STG(q, 0, 0, 0);
    STG(q, 1, 0, 0);
  }
  WAITV0();
  BARRIER();

  const int aswz = (lr & 7) << 4;
  for (int t = 0; t < 16; t++) {
    const int cur = t & 1, nb = cur ^ 1;
    const int kb1 = (t + 1) * 128;
    const char* Ab = lds + cur * 32768;
    const char* Bb = lds + 65536 + cur * 32768;
    bf16x8 af[4][2], bfr[2][2];

    // ---- phase 0: (mh=0, nh=0) ----
    if (t < 15) { STG(0, 0, kb1, nb); STG(0, 1, kb1, nb); }
    if (t < 15) asm volatile("s_waitcnt vmcnt(6)" ::: "memory");
    else        asm volatile("s_waitcnt vmcnt(4)" ::: "memory");
    BARRIER();
#pragma unroll
    for (int i = 0; i < 4; i++)
#pragma unroll
      for (int kk = 0; kk < 2; kk++)
        af[i][kk] = *(const bf16x8*)(Ab + (wr * 128 + i * 16 + lr) * 128 +
                                     ((kk * 64 + lg * 16) ^ aswz));
#pragma unroll
    for (int j = 0; j < 2; j++)
#pragma unroll
      for (int kk = 0; kk < 2; kk++)
        bfr[j][kk] = *(const bf16x8*)(Bb + (wc * 64 + j * 16 + lr) * 128 +
                                      ((kk * 64 + lg * 16) ^ aswz));
    __builtin_amdgcn_s_setprio(1);
#pragma unroll
    for (int kk = 0; kk < 2; kk++)
#pragma unroll
      for (int i = 0; i < 4; i++)
#pragma unroll
        for (int j = 0; j < 2; j++)
          acc[i][j] = __builtin_amdgcn_mfma_f32_16x16x32_bf16(
              af[i][kk], bfr[j][kk], acc[i][j], 0, 0, 0);
    __builtin_amdgcn_s_setprio(0);

    // ---- phase 1: (mh=1, nh=0), reuse bfr ----
    if (t < 15) { STG(1, 0, kb1, nb); STG(1, 1, kb1, nb); }
    if (t < 15) asm volatile("s_waitcnt vmcnt(6)" ::: "memory");
    else        asm volatile("s_waitcnt vmcnt(2)" ::: "memory");
    BARRIER();
#pragma unroll
    for (int i = 0; i < 4; i++)
#pragma unroll
      for (int kk = 0; kk < 2; kk++)
        af[i][kk] = *(const bf16x8*)(Ab + (wr * 128 + 64 + i * 16 + lr) * 128 +
                                     ((kk * 64 + lg * 16) ^ aswz));
    __builtin_amdgcn_s_setprio(1);
#pragma unroll
    for (int kk = 0; kk < 2; kk++)
#pragma unroll
      for (int i = 0; i < 4; i++)
#pragma unroll
        for (int j = 0; j < 2; j++)
          acc[4 + i][j] = __builtin_amdgcn_mfma_f32_16x16x32_bf16(
              af[i][kk], bfr[j][kk], acc[4 + i][j], 0, 0, 0);
    __builtin_amdgcn_s_setprio(0);

    // ---- phase 2: (mh=1, nh=1), reuse af ----
    if (t < 15) { STG(2, 0, kb1, nb); STG(2, 1, kb1, nb); }
    if (t < 15) asm volatile("s_waitcnt vmcnt(6)" ::: "memory");
    else        asm volatile("s_waitcnt vmcnt(0)" ::: "memory");
    BARRIER();
#pragma unroll
    for (int j = 0; j < 2; j++)
#pragma unroll
      for (int kk = 0; kk < 2; kk++)
        bfr[j][kk] = *(const bf16x8*)(Bb + (wc * 64 + 32 + j * 16 + lr) * 128 +
                                      ((kk * 64 + lg * 16) ^ aswz));
    __builtin_amdgcn_s_setprio(1);
#pragma unroll
    for (int kk = 0; kk < 2; kk++)
#pragma unroll
      for (int i = 0; i < 4; i++)
#pragma unroll
        for (int j = 0; j < 2; j++)
          acc[4 + i][2 + j] = __builtin_amdgcn_mfma_f32_16x16x32_bf16(
              af[i][kk], bfr[j][kk], acc[4 + i][2 + j], 0, 0, 0);
    __builtin_amdgcn_s_setprio(0);

    // ---- phase 3: (mh=0, nh=1), reuse bfr ----
    if (t < 15) { STG(3, 0, kb1, nb); STG(3, 1, kb1, nb); }
    BARRIER();
#pragma unroll
    for (int i = 0; i < 4; i++)
#pragma unroll
      for (int kk = 0; kk < 2; kk++)
        af[i][kk] = *(const bf16x8*)(Ab + (wr * 128 + i * 16 + lr) * 128 +
                                     ((kk * 64 + lg * 16) ^ aswz));
    __builtin_amdgcn_s_setprio(1);
#pragma unroll
    for (int kk = 0; kk < 2; kk++)
#pragma unroll
      for (int i = 0; i < 4; i++)
#pragma unroll
        for (int j = 0; j < 2; j++)
          acc[i][2 + j] = __builtin_amdgcn_mfma_f32_16x16x32_bf16(
              af[i][kk], bfr[j][kk], acc[i][2 + j], 0, 0, 0);
    __builtin_amdgcn_s_setprio(0);
    BARRIER();  // end-of-iter: all reads of buf[cur] done before it's restaged
  }
#undef STG

  // stage rope tables (256 rows x 32 freqs) into dead LDS, XOR-swizzled
  {
    float4* cosL4 = (float4*)lds;
    float4* sinL4 = (float4*)(lds + 65536);
    const float4* cg = (const float4*)(cosT + (size_t)(m0 & 2047) * 32);
    const float4* sg = (const float4*)(sinT + (size_t)(m0 & 2047) * 32);
#pragma unroll
    for (int i = 0; i < 4; i++) {
      const int c = tid + i * 512;  // [0,2048)
      const int rw = c >> 3, f4 = c & 7;
      const int slot = rw * 8 + (f4 ^ (((rw >> 2) & 3) << 1));
      cosL4[slot] = cg[c];
      sinL4[slot] = sg[c];
    }
  }
  BARRIER();
  const float* cosL = (const float*)lds;
  const float* sinL = (const float*)(lds + 65536);

  // epilogue: fused RoPE + scatter (Q scaled log2e/8)
#pragma unroll
  for (int mi = 0; mi < 8; mi++) {
#pragma unroll
    for (int ni = 0; ni < 4; ni++) {
      const int col = n0 + wc * 64 + ni * 16 + lr;
      const int which = col >> 10;
      const int hd = col & 1023;
      const int h = hd >> 6, d = hd & 63;
      const int fi = d >> 1;
      const float sgn = (lr & 1) ? 1.0f : -1.0f;
      const float qsc = (which == 0) ? 0.18033688f : 1.0f;  // log2(e)/8
      float vv[4];
#pragma unroll
      for (int r = 0; r < 4; r++) {
        const int row = m0 + wr * 128 + mi * 16 + lg * 4 + r;
        float v = acc[mi][ni][r];
        if (which < 2) {
          float p = __shfl_xor(v, 1, 64);
          const int fj = fi ^ (((row >> 2) & 3) << 3);
          const int lo = (row & 255) * 32 + fj;
          v = (v * cosL[lo] + sgn * p * sinL[lo]) * qsc;
        }
        vv[r] = v;
      }
      const unsigned int pk0 = cvt_pk_bf16(vv[0], vv[1]);
      const unsigned int pk1 = cvt_pk_bf16(vv[2], vv[3]);
#pragma unroll
      for (int r = 0; r < 4; r++) {
        const int row = m0 + wr * 128 + mi * 16 + lg * 4 + r;
        const int b = row >> 11, tt = row & 2047;
        const unsigned int pk = (r < 2) ? pk0 : pk1;
        const unsigned short bv =
            (unsigned short)((r & 1) ? (pk >> 16) : (pk & 0xFFFFu));
        size_t bh = (size_t)(b * NH + h);
        if (which == 0)
          Qo[(bh * T_ + tt) * HD + d] = bv;
        else if (which == 1)
          Ko[(bh * T_ + tt) * HD + d] = bv;
        else
          VTo[(bh * HD + d) * T_ + tt] = bv;
      }
    }
  }
}

// Proj GEMM: A [8192][1024] bf16 @ Bt [1024][1024] bf16 -> C f32 [8192][1024]
__global__ __launch_bounds__(256, 2) void gemm_proj(
    const unsigned short* __restrict__ A, const unsigned short* __restrict__ Bt,
    float* __restrict__ C) {
  __shared__ __align__(16) unsigned short As[2 * 8192];
  __shared__ __align__(16) unsigned short Bs[2 * 8192];
  const int bid = blockIdx.x;
  const int xcd = bid & 7;
  const int cc = bid >> 3;  // [0,64)
  const int m0 = (xcd * 8 + cc / 8) * 128;
  const int n0 = (cc % 8) * 128;
  const int tid = threadIdx.x;
  const int w = tid >> 6, l = tid & 63;
  const int wr = w >> 1, wc = w & 1;
  const int lr = l & 15, lg = l >> 4;
  f32x4 acc[4][4];
#pragma unroll
  for (int i = 0; i < 4; i++)
#pragma unroll
    for (int j = 0; j < 4; j++) acc[i][j] = (f32x4)0.f;

  GEMM_MAIN2(As, Bs, A, Bt, acc)

#pragma unroll
  for (int mi = 0; mi < 4; mi++) {
#pragma unroll
    for (int ni = 0; ni < 4; ni++) {
      const int col = n0 + wc * 64 + ni * 16 + lr;
#pragma unroll
      for (int r = 0; r < 4; r++) {
        const int row = m0 + wr * 64 + mi * 16 + lg * 4 + r;
        C[(size_t)row * 1024 + col] = acc[mi][ni][r];
      }
    }
  }
}

// ---------------- Flash attention v7: K,V both 3-buffered, distance 3 -------
__global__ __launch_bounds__(256, 3) void attn_kernel(
    const unsigned short* __restrict__ Q, const unsigned short* __restrict__ K,
    const unsigned short* __restrict__ VT, unsigned short* __restrict__ O) {
  __shared__ __align__(16) unsigned short Ks[3][4096];  // [64 kv][64 d]
  __shared__ __align__(16) unsigned short Vs[3][4096];  // [64 d][64 t]

  const int blk = blockIdx.x;
  const int bh = (blk & 7) * 8 + ((blk >> 3) & 7);
  const int r4 = blk >> 8, g4 = (blk >> 6) & 3;
  const int qt = (r4 == 0) ? (15 - g4)
               : (r4 == 1) ? (8 + g4)
               : (r4 == 2) ? (7 - g4)
                           : g4;
  const int b = bh >> 4, h = bh & 15;
  const int tid = threadIdx.x;
  const int w = tid >> 6, l = tid & 63;
  const int q31 = l & 31, h5 = l >> 5;
  const int q0w = qt * 128 + w * 32;
  const int q_abs = q0w + q31;

  const unsigned short* Qb = Q + (size_t)bh * T_ * HD;
  const char* Kc = (const char*)(K + (size_t)bh * T_ * HD);
  const char* Vc = (const char*)(VT + (size_t)bh * HD * T_);

  const int c0 = (w * 2) * 64 + l;
  const int c1 = (w * 2 + 1) * 64 + l;
  const int r0 = c0 >> 3, r1 = c1 >> 3;
  const int sw0 = ((c0 & 7) * 16) ^ ((r0 & 7) << 4);
  const int sw1 = ((c1 & 7) * 16) ^ ((r1 & 7) << 4);
  const char* pK0 = Kc + r0 * 128 + sw0;
  const char* pK1 = Kc + r1 * 128 + sw1;
  const char* pV0 = Vc + (size_t)r0 * (T_ * 2) + sw0;
  const char* pV1 = Vc + (size_t)r1 * (T_ * 2) + sw1;

#define SK(buf, tile)                                                       \
  do {                                                                      \
    size_t kb = (size_t)(tile) * 8192;                                      \
    gll16(pK0 + kb, (char*)Ks[buf] + (w * 2) * 1024);                       \
    gll16(pK1 + kb, (char*)Ks[buf] + (w * 2 + 1) * 1024);                   \
  } while (0)
#define SV(buf, tile)                                                       \
  do {                                                                      \
    size_t vb = (size_t)(tile) * 128;                                       \
    gll16(pV0 + vb, (char*)Vs[buf] + (w * 2) * 1024);                       \
    gll16(pV1 + vb, (char*)Vs[buf] + (w * 2 + 1) * 1024);                   \
  } while (0)

  bf16x8 qf[4];
#pragma unroll
  for (int ks4 = 0; ks4 < 4; ks4++)
    qf[ks4] = *(const bf16x8*)(Qb + (size_t)q_abs * HD + ks4 * 16 + h5 * 8);

  f32x16 ot0 = (f32x16)0.f, ot1 = (f32x16)0.f;
  float m_reg = -1e30f, lrow = 0.f;

  const int nt = 2 * qt + 2;
  const int jmax = q0w >> 6;

  SK(0, 0);
  SV(0, 0);
  if (nt > 1) {
    SK(1, 1);
    SV(1, 1);
  }
  if (nt > 2) {
    SK(2, 2);
    SV(2, 2);
  }

  int cur3 = 0;
  for (int j = 0; j < nt; j++) {
    if (j <= nt - 3) {
      asm volatile("s_waitcnt vmcnt(8)" ::: "memory");
    } else if (j == nt - 2) {
      asm volatile("s_waitcnt vmcnt(4)" ::: "memory");
    } else {
      asm volatile("s_waitcnt vmcnt(0)" ::: "memory");
    }
    BARRIER();
    if (j <= jmax) {
      f32x16 st[2];
      st[0] = (f32x16)0.f;
      st[1] = (f32x16)0.f;
      __builtin_amdgcn_s_setprio(1);
#pragma unroll
      for (int sub = 0; sub < 2; sub++) {
        const int row = sub * 32 + q31;
        const int sw = (row & 7) << 4;
#pragma unroll
        for (int ks4 = 0; ks4 < 4; ks4++) {
          bf16x8 kf = *(const bf16x8*)((const char*)Ks[cur3] + row * 128 +
                                       ((ks4 * 32 + h5 * 16) ^ sw));
          st[sub] = __builtin_amdgcn_mfma_f32_32x32x16_bf16(kf, qf[ks4],
                                                            st[sub], 0, 0, 0);
        }
      }
      __builtin_amdgcn_s_setprio(0);
      if (j == jmax) {
        const int t0 = j * 64;
#pragma unroll
        for (int sub = 0; sub < 2; sub++)
#pragma unroll
          for (int r = 0; r < 16; r++) {
            int kv_abs = t0 + sub * 32 + (r & 3) + 8 * (r >> 2) + 4 * h5;
            if (kv_abs > q_abs) st[sub][r] = -1e30f;
          }
      }
      float pmax;
      {
        float q0m = -1e30f, q1m = -1e30f;
#pragma unroll
        for (int r = 0; r < 16; r += 4) {
          q0m = fmaxf(q0m, fmaxf(fmaxf(st[0][r], st[0][r + 1]),
                                 fmaxf(st[0][r + 2], st[0][r + 3])));
          q1m = fmaxf(q1m, fmaxf(fmaxf(st[1][r], st[1][r + 1]),
                                 fmaxf(st[1][r + 2], st[1][r + 3])));
        }
        pmax = fmaxf(q0m, q1m);
      }
      pmax = fmaxf(pmax, __shfl_xor(pmax, 32, 64));
      const int defer = __all(pmax - m_reg <= 8.0f);
      if (!defer) {
        float mnew = fmaxf(m_reg, pmax);
        float alpha = exp2_fast(m_reg - mnew);
        m_reg = mnew;
        lrow *= alpha;
#pragma unroll
        for (int r = 0; r < 16; r++) {
          ot0[r] *= alpha;
          ot1[r] *= alpha;
        }
      }
      float rsum = 0.f;
#pragma unroll
      for (int sub = 0; sub < 2; sub++)
#pragma unroll
        for (int r = 0; r < 16; r++) {
          float p = exp2_fast(st[sub][r] - m_reg);
          st[sub][r] = p;
          rsum += p;
        }
      rsum += __shfl_xor(rsum, 32, 64);
      lrow += rsum;
      unsigned int pk[2][8];
#pragma unroll
      for (int sub = 0; sub < 2; sub++)
#pragma unroll
        for (int g = 0; g < 4; g++) {
          pk[sub][2 * g] = cvt_pk_bf16(st[sub][4 * g + 0], st[sub][4 * g + 1]);
          pk[sub][2 * g + 1] =
              cvt_pk_bf16(st[sub][4 * g + 2], st[sub][4 * g + 3]);
        }
      bf16x8 pf[4];
#pragma unroll
      for (int sub = 0; sub < 2; sub++)
#pragma unroll
        for (int s = 0; s < 2; s++) {
          unsigned int a0 = pk[sub][4 * s + 0], a1 = pk[sub][4 * s + 1];
          unsigned int b0 = pk[sub][4 * s + 2], b1 = pk[sub][4 * s + 3];
          unsigned int send0 = h5 ? a0 : b0, send1 = h5 ? a1 : b1;
          unsigned int sh0 = (unsigned int)__shfl_xor((int)send0, 32, 64);
          unsigned int sh1 = (unsigned int)__shfl_xor((int)send1, 32, 64);
          unsigned int ow0 = h5 ? b0 : a0, ow1 = h5 ? b1 : a1;
          u32x4 fu;
          fu[0] = h5 ? sh0 : ow0;
          fu[1] = h5 ? sh1 : ow1;
          fu[2] = h5 ? ow0 : sh0;
          fu[3] = h5 ? ow1 : sh1;
          pf[sub * 2 + s] = *(bf16x8*)&fu;
        }
      __builtin_amdgcn_s_setprio(1);
#pragma unroll
      for (int ks = 0; ks < 4; ks++) {
        const int colb = ks * 32 + h5 * 16;
        {
          const int row = q31;
          bf16x8 vf = *(const bf16x8*)((const char*)Vs[cur3] + row * 128 +
                                       (colb ^ ((row & 7) << 4)));
          ot0 = __builtin_amdgcn_mfma_f32_32x32x16_bf16(vf, pf[ks], ot0, 0, 0, 0);
        }
        {
          const int row = 32 + q31;
          bf16x8 vf = *(const bf16x8*)((const char*)Vs[cur3] + row * 128 +
                                       (colb ^ ((row & 7) << 4)));
          ot1 = __builtin_amdgcn_mfma_f32_32x32x16_bf16(vf, pf[ks], ot1, 0, 0, 0);
        }
      }
      __builtin_amdgcn_s_setprio(0);
    }
    BARRIER();
    if (j + 3 < nt) {
      SK(cur3, j + 3);
      SV(cur3, j + 3);
    }
    cur3 = (cur3 == 2) ? 0 : cur3 + 1;
  }

  const float rcpl = 1.0f / lrow;
  unsigned short* Orow = O + ((size_t)b * T_ + q_abs) * DM + h * HD;
#pragma unroll
  for (int rg = 0; rg < 4; rg++) {
    uint2 s0;
    s0.x = cvt_pk_bf16(ot0[4 * rg + 0] * rcpl, ot0[4 * rg + 1] * rcpl);
    s0.y = cvt_pk_bf16(ot0[4 * rg + 2] * rcpl, ot0[4 * rg + 3] * rcpl);
    *(uint2*)(Orow + 8 * rg + 4 * h5) = s0;
    uint2 s1;
    s1.x = cvt_pk_bf16(ot1[4 * rg + 0] * rcpl, ot1[4 * rg + 1] * rcpl);
    s1.y = cvt_pk_bf16(ot1[4 * rg + 2] * rcpl, ot1[4 * rg + 3] * rcpl);
    *(uint2*)(Orow + 32 + 8 * rg + 4 * h5) = s1;
  }
#undef SK
#undef SV
}

extern "C" void kernel_launch(void* const* d_in, const int* in_sizes, int n_in,
                              void* d_out, int out_size, void* d_ws,
                              size_t ws_size, hipStream_t stream) {
  const float* x = (const float*)d_in[0];
  const float* cosT = (const float*)d_in[1];
  const float* sinT = (const float*)d_in[2];
  const float* w_qkv = (const float*)d_in[3];
  const float* w_proj = (const float*)d_in[4];
  float* out = (float*)d_out;

  char* ws = (char*)d_ws;
  unsigned short* x16 = (unsigned short*)(ws);                  // 16 MB
  unsigned short* wqkvT = (unsigned short*)(ws + (16 << 20));   // 6 MB
  unsigned short* wprojT = (unsigned short*)(ws + (22 << 20));  // 2 MB
  unsigned short* Qb = (unsigned short*)(ws + (24 << 20));      // 16 MB
  unsigned short* Kb = (unsigned short*)(ws + (40 << 20));      // 16 MB
  unsigned short* VTb = (unsigned short*)(ws + (56 << 20));     // 16 MB
  unsigned short* Ob = x16;  // reuse: x16 dead after gemm_qkv

  prep_kernel<<<6144, 256, 0, stream>>>(x, x16, w_qkv, wqkvT, w_proj, wprojT);
  gemm_qkv<<<384, 512, 0, stream>>>(x16, wqkvT, cosT, sinT, Qb, Kb, VTb);
  attn_kernel<<<1024, 256, 0, stream>>>(Qb, Kb, VTb, Ob);
  gemm_proj<<<512, 256, 0, stream>>>(Ob, wprojT, out);
}

// Round 16
// 172.662 us; speedup vs baseline: 1.1146x; 1.1146x over previous
//
#include <hip/hip_runtime.h>
#include <cstdint>
#include <cstddef>

typedef __attribute__((ext_vector_type(8))) short bf16x8;
typedef __attribute__((ext_vector_type(4))) float f32x4;
typedef __attribute__((ext_vector_type(16))) float f32x16;
typedef __attribute__((ext_vector_type(4))) unsigned int u32x4;

#define B_ 4
#define T_ 2048
#define DM 1024
#define NH 16
#define HD 64

static __device__ __forceinline__ unsigned short f2bf(float f) {
  union { float f; unsigned int u; } v; v.f = f;
  unsigned int r = v.u + 0x7FFFu + ((v.u >> 16) & 1u);
  return (unsigned short)(r >> 16);
}
static __device__ __forceinline__ float exp2_fast(float x) {
  float r;
  asm volatile("v_exp_f32 %0, %1" : "=v"(r) : "v"(x));
  return r;
}
// packs bf16(a) into lo16, bf16(b) into hi16 (RTNE) — T12 primitive
static __device__ __forceinline__ unsigned int cvt_pk_bf16(float a, float b) {
  unsigned int r;
  asm("v_cvt_pk_bf16_f32 %0, %1, %2" : "=v"(r) : "v"(a), "v"(b));
  return r;
}

static __device__ __forceinline__ void gll16(const void* g, void* l) {
  __builtin_amdgcn_global_load_lds(
      (const __attribute__((address_space(1))) void*)g,
      (__attribute__((address_space(3))) void*)l, 16, 0, 0);
}

#define BARRIER() do { asm volatile("" ::: "memory"); __builtin_amdgcn_s_barrier(); asm volatile("" ::: "memory"); } while (0)
#define WAITV0() asm volatile("s_waitcnt vmcnt(0)" ::: "memory")

// ---------------- merged prep: cast x->bf16 + transpose both weights --------
__global__ __launch_bounds__(256) void prep_kernel(
    const float* __restrict__ x, unsigned short* __restrict__ x16,
    const float* __restrict__ w_qkv, unsigned short* __restrict__ wqkvT,
    const float* __restrict__ w_proj, unsigned short* __restrict__ wprojT) {
  __shared__ unsigned short tile[32][33];
  const int bid = blockIdx.x;
  const int tid = threadIdx.x;
  if (bid < 2048) {
    const int n8 = (B_ * T_ * DM) / 8;  // 1048576
    for (int i = bid * 256 + tid; i < n8; i += 2048 * 256) {
      const float4* p = (const float4*)(x + (size_t)i * 8);
      float4 a = p[0], b = p[1];
      u32x4 o;
      o[0] = cvt_pk_bf16(a.x, a.y);
      o[1] = cvt_pk_bf16(a.z, a.w);
      o[2] = cvt_pk_bf16(b.x, b.y);
      o[3] = cvt_pk_bf16(b.z, b.w);
      *(u32x4*)(x16 + (size_t)i * 8) = o;
    }
    return;
  }
  const float* in;
  unsigned short* out;
  int R, C, bx, by;
  if (bid < 5120) {
    const int b2 = bid - 2048;  // [0,3072)
    in = w_qkv; out = wqkvT; R = 1024; C = 3072;
    bx = b2 % 96; by = b2 / 96;
  } else {
    const int b2 = bid - 5120;  // [0,1024)
    in = w_proj; out = wprojT; R = 1024; C = 1024;
    bx = b2 % 32; by = b2 / 32;
  }
  const int c0 = bx * 32, r0 = by * 32;
  const int tx = tid & 31, ty = tid >> 5;
#pragma unroll
  for (int j = 0; j < 32; j += 8) {
    float v = in[(size_t)(r0 + ty + j) * C + c0 + tx];
    tile[tx][ty + j] = f2bf(v);
  }
  __syncthreads();
#pragma unroll
  for (int j = 0; j < 32; j += 8) {
    out[(size_t)(c0 + ty + j) * R + r0 + tx] = tile[ty + j][tx];
  }
}

// ---------------- GEMM core v1 (m97 single-buffer) --------------------------
#define GEMM_MAIN(As, Bs, Agl, Bgl, acc)                                     \
  {                                                                          \
    const char* gA = (const char*)(Agl) +                                    \
                     (size_t)(m0 + (tid >> 3)) * 2048 +                      \
                     (((tid & 7) ^ ((tid >> 3) & 7)) << 4);                  \
    const char* gB = (const char*)(Bgl) +                                    \
                     (size_t)(n0 + (tid >> 3)) * 2048 +                      \
                     (((tid & 7) ^ ((tid >> 3) & 7)) << 4);                  \
    for (int k0 = 0; k0 < 2048; k0 += 128) {                                 \
      _Pragma("unroll") for (int i = 0; i < 4; i++) {                        \
        gll16(gA + (size_t)i * 65536 + k0, (char*)(As) + i * 4096 + w * 1024);\
        gll16(gB + (size_t)i * 65536 + k0, (char*)(Bs) + i * 4096 + w * 1024);\
      }                                                                      \
      WAITV0();                                                              \
      BARRIER();                                                             \
      _Pragma("unroll") for (int kk = 0; kk < 2; kk++) {                     \
        bf16x8 af[4], bfr[4];                                                \
        const int ko = (kk * 64 + lg * 16) ^ ((lr & 7) << 4);                \
        _Pragma("unroll") for (int mi = 0; mi < 4; mi++)                     \
            af[mi] = *(const bf16x8*)((const char*)(As) +                    \
                                      (wr * 64 + mi * 16 + lr) * 128 + ko);  \
        _Pragma("unroll") for (int ni = 0; ni < 4; ni++)                     \
            bfr[ni] = *(const bf16x8*)((const char*)(Bs) +                   \
                                       (wc * 64 + ni * 16 + lr) * 128 + ko); \
        _Pragma("unroll") for (int mi = 0; mi < 4; mi++)                     \
            _Pragma("unroll") for (int ni = 0; ni < 4; ni++)                 \
                acc[mi][ni] = __builtin_amdgcn_mfma_f32_16x16x32_bf16(       \
                    af[mi], bfr[ni], acc[mi][ni], 0, 0, 0);                  \
      }                                                                      \
      BARRIER();                                                             \
    }                                                                        \
  }

// ---------------- GEMM core v2 (2-phase counted-vmcnt dbuf; proj only) ------
#define GEMM_MAIN2(As, Bs, Agl, Bgl, acc)                                    \
  {                                                                          \
    const char* gA = (const char*)(Agl) +                                    \
                     (size_t)(m0 + (tid >> 3)) * 2048 +                      \
                     (((tid & 7) ^ ((tid >> 3) & 7)) << 4);                  \
    const char* gB = (const char*)(Bgl) +                                    \
                     (size_t)(n0 + (tid >> 3)) * 2048 +                      \
                     (((tid & 7) ^ ((tid >> 3) & 7)) << 4);                  \
    _Pragma("unroll") for (int i = 0; i < 4; i++) {                          \
      gll16(gA + (size_t)i * 65536, (char*)(As) + i * 4096 + w * 1024);      \
      gll16(gB + (size_t)i * 65536, (char*)(Bs) + i * 4096 + w * 1024);      \
    }                                                                        \
    for (int t = 0; t < 16; t++) {                                           \
      const int cur = (t & 1) << 14;                                         \
      if (t < 15) {                                                          \
        const int nxt = ((t + 1) & 1) << 14;                                 \
        const int k0 = (t + 1) * 128;                                        \
        _Pragma("unroll") for (int i = 0; i < 4; i++) {                      \
          gll16(gA + (size_t)i * 65536 + k0,                                 \
                (char*)(As) + nxt + i * 4096 + w * 1024);                    \
          gll16(gB + (size_t)i * 65536 + k0,                                 \
                (char*)(Bs) + nxt + i * 4096 + w * 1024);                    \
        }                                                                    \
        asm volatile("s_waitcnt vmcnt(8)" ::: "memory");                     \
      } else {                                                               \
        asm volatile("s_waitcnt vmcnt(0)" ::: "memory");                     \
      }                                                                      \
      BARRIER();                                                             \
      _Pragma("unroll") for (int kk = 0; kk < 2; kk++) {                     \
        bf16x8 af[4], bfr[4];                                                \
        const int ko = (kk * 64 + lg * 16) ^ ((lr & 7) << 4);                \
        _Pragma("unroll") for (int mi = 0; mi < 4; mi++)                     \
            af[mi] = *(const bf16x8*)((const char*)(As) + cur +              \
                                      (wr * 64 + mi * 16 + lr) * 128 + ko);  \
        _Pragma("unroll") for (int ni = 0; ni < 4; ni++)                     \
            bfr[ni] = *(const bf16x8*)((const char*)(Bs) + cur +             \
                                       (wc * 64 + ni * 16 + lr) * 128 + ko); \
        _Pragma("unroll") for (int mi = 0; mi < 4; mi++)                     \
            _Pragma("unroll") for (int ni = 0; ni < 4; ni++)                 \
                acc[mi][ni] = __builtin_amdgcn_mfma_f32_16x16x32_bf16(       \
                    af[mi], bfr[ni], acc[mi][ni], 0, 0, 0);                  \
      }                                                                      \
      BARRIER();                                                             \
    }                                                                        \
  }

// QKV GEMM + fused RoPE epilogue (cos/sin staged in LDS, XOR-swizzled).
// Outputs Q [bh][t][64] (scaled log2e/8), K [bh][t][64], VT [bh][64][t].
// Grid 1536 1D, XCD-chunked, n-major within XCD.
__global__ __launch_bounds__(256, 4) void gemm_qkv(
    const unsigned short* __restrict__ A, const unsigned short* __restrict__ Bt,
    const float* __restrict__ cosT, const float* __restrict__ sinT,
    unsigned short* __restrict__ Qo, unsigned short* __restrict__ Ko,
    unsigned short* __restrict__ VTo) {
  __shared__ __align__(16) unsigned short As[128 * 64];
  __shared__ __align__(16) unsigned short Bs[128 * 64];
  const int bid = blockIdx.x;
  const int xcd = bid & 7;
  const int cc = bid >> 3;  // [0,192): n-major within XCD
  const int m0 = (xcd * 8 + (cc & 7)) * 128;
  const int n0 = (cc >> 3) * 128;
  const int tid = threadIdx.x;
  const int w = tid >> 6, l = tid & 63;
  const int wr = w >> 1, wc = w & 1;
  const int lr = l & 15, lg = l >> 4;
  f32x4 acc[4][4];
#pragma unroll
  for (int i = 0; i < 4; i++)
#pragma unroll
    for (int j = 0; j < 4; j++) acc[i][j] = (f32x4)0.f;

  GEMM_MAIN(As, Bs, A, Bt, acc)

  // stage this block's cos/sin slice into now-dead As/Bs, XOR-swizzled
  {
    float4* cosL4 = (float4*)As;
    float4* sinL4 = (float4*)Bs;
    const float4* cg = (const float4*)(cosT + (size_t)(m0 & 2047) * 32);
    const float4* sg = (const float4*)(sinT + (size_t)(m0 & 2047) * 32);
#pragma unroll
    for (int i = 0; i < 4; i++) {
      const int c = tid + i * 256;
      const int rw = c >> 3, f4 = c & 7;
      const int slot = rw * 8 + (f4 ^ (((rw >> 2) & 3) << 1));
      cosL4[slot] = cg[c];
      sinL4[slot] = sg[c];
    }
  }
  BARRIER();
  const float* cosL = (const float*)As;
  const float* sinL = (const float*)Bs;

#pragma unroll
  for (int mi = 0; mi < 4; mi++) {
#pragma unroll
    for (int ni = 0; ni < 4; ni++) {
      const int col = n0 + wc * 64 + ni * 16 + lr;
      const int which = col >> 10;
      const int hd = col & 1023;
      const int h = hd >> 6, d = hd & 63;
      const int fi = d >> 1;
      const float sgn = (lr & 1) ? 1.0f : -1.0f;
      const float qsc = (which == 0) ? 0.18033688f : 1.0f;  // log2(e)/8
      float vv[4];
#pragma unroll
      for (int r = 0; r < 4; r++) {
        const int row = m0 + wr * 64 + mi * 16 + lg * 4 + r;
        float v = acc[mi][ni][r];
        if (which < 2) {
          float p = __shfl_xor(v, 1, 64);
          const int fj = fi ^ (((row >> 2) & 3) << 3);
          const int lo = (row & 127) * 32 + fj;
          v = (v * cosL[lo] + sgn * p * sinL[lo]) * qsc;
        }
        vv[r] = v;
      }
      const unsigned int pk0 = cvt_pk_bf16(vv[0], vv[1]);
      const unsigned int pk1 = cvt_pk_bf16(vv[2], vv[3]);
#pragma unroll
      for (int r = 0; r < 4; r++) {
        const int row = m0 + wr * 64 + mi * 16 + lg * 4 + r;
        const int b = row >> 11, tt = row & 2047;
        const unsigned int pk = (r < 2) ? pk0 : pk1;
        const unsigned short bv =
            (unsigned short)((r & 1) ? (pk >> 16) : (pk & 0xFFFFu));
        size_t bh = (size_t)(b * NH + h);
        if (which == 0)
          Qo[(bh * T_ + tt) * HD + d] = bv;
        else if (which == 1)
          Ko[(bh * T_ + tt) * HD + d] = bv;
        else
          VTo[(bh * HD + d) * T_ + tt] = bv;
      }
    }
  }
}

// Proj GEMM: A [8192][1024] bf16 @ Bt [1024][1024] bf16 -> C f32 [8192][1024]
// Grid: 512 1D (= exactly 2 blocks/CU) -> 64KB dbuf LDS is occupancy-neutral.
__global__ __launch_bounds__(256, 2) void gemm_proj(
    const unsigned short* __restrict__ A, const unsigned short* __restrict__ Bt,
    float* __restrict__ C) {
  __shared__ __align__(16) unsigned short As[2 * 8192];
  __shared__ __align__(16) unsigned short Bs[2 * 8192];
  const int bid = blockIdx.x;
  const int xcd = bid & 7;
  const int cc = bid >> 3;  // [0,64)
  const int m0 = (xcd * 8 + cc / 8) * 128;
  const int n0 = (cc % 8) * 128;
  const int tid = threadIdx.x;
  const int w = tid >> 6, l = tid & 63;
  const int wr = w >> 1, wc = w & 1;
  const int lr = l & 15, lg = l >> 4;
  f32x4 acc[4][4];
#pragma unroll
  for (int i = 0; i < 4; i++)
#pragma unroll
    for (int j = 0; j < 4; j++) acc[i][j] = (f32x4)0.f;

  GEMM_MAIN2(As, Bs, A, Bt, acc)

#pragma unroll
  for (int mi = 0; mi < 4; mi++) {
#pragma unroll
    for (int ni = 0; ni < 4; ni++) {
      const int col = n0 + wc * 64 + ni * 16 + lr;
#pragma unroll
      for (int r = 0; r < 4; r++) {
        const int row = m0 + wr * 64 + mi * 16 + lg * 4 + r;
        C[(size_t)row * 1024 + col] = acc[mi][ni][r];
      }
    }
  }
}

// ---------------- Flash attention v7: K,V both 3-buffered, distance 3 -------
__global__ __launch_bounds__(256, 3) void attn_kernel(
    const unsigned short* __restrict__ Q, const unsigned short* __restrict__ K,
    const unsigned short* __restrict__ VT, unsigned short* __restrict__ O) {
  __shared__ __align__(16) unsigned short Ks[3][4096];  // [64 kv][64 d]
  __shared__ __align__(16) unsigned short Vs[3][4096];  // [64 d][64 t]

  const int blk = blockIdx.x;
  const int bh = (blk & 7) * 8 + ((blk >> 3) & 7);
  const int r4 = blk >> 8, g4 = (blk >> 6) & 3;
  const int qt = (r4 == 0) ? (15 - g4)
               : (r4 == 1) ? (8 + g4)
               : (r4 == 2) ? (7 - g4)
                           : g4;
  const int b = bh >> 4, h = bh & 15;
  const int tid = threadIdx.x;
  const int w = tid >> 6, l = tid & 63;
  const int q31 = l & 31, h5 = l >> 5;
  const int q0w = qt * 128 + w * 32;
  const int q_abs = q0w + q31;

  const unsigned short* Qb = Q + (size_t)bh * T_ * HD;
  const char* Kc = (const char*)(K + (size_t)bh * T_ * HD);
  const char* Vc = (const char*)(VT + (size_t)bh * HD * T_);

  const int c0 = (w * 2) * 64 + l;
  const int c1 = (w * 2 + 1) * 64 + l;
  const int r0 = c0 >> 3, r1 = c1 >> 3;
  const int sw0 = ((c0 & 7) * 16) ^ ((r0 & 7) << 4);
  const int sw1 = ((c1 & 7) * 16) ^ ((r1 & 7) << 4);
  const char* pK0 = Kc + r0 * 128 + sw0;
  const char* pK1 = Kc + r1 * 128 + sw1;
  const char* pV0 = Vc + (size_t)r0 * (T_ * 2) + sw0;
  const char* pV1 = Vc + (size_t)r1 * (T_ * 2) + sw1;

#define SK(buf, tile)                                                       \
  do {                                                                      \
    size_t kb = (size_t)(tile) * 8192;                                      \
    gll16(pK0 + kb, (char*)Ks[buf] + (w * 2) * 1024);                       \
    gll16(pK1 + kb, (char*)Ks[buf] + (w * 2 + 1) * 1024);                   \
  } while (0)
#define SV(buf, tile)                                                       \
  do {                                                                      \
    size_t vb = (size_t)(tile) * 128;                                       \
    gll16(pV0 + vb, (char*)Vs[buf] + (w * 2) * 1024);                       \
    gll16(pV1 + vb, (char*)Vs[buf] + (w * 2 + 1) * 1024);                   \
  } while (0)

  bf16x8 qf[4];
#pragma unroll
  for (int ks4 = 0; ks4 < 4; ks4++)
    qf[ks4] = *(const bf16x8*)(Qb + (size_t)q_abs * HD + ks4 * 16 + h5 * 8);

  f32x16 ot0 = (f32x16)0.f, ot1 = (f32x16)0.f;
  float m_reg = -1e30f, lrow = 0.f;

  const int nt = 2 * qt + 2;
  const int jmax = q0w >> 6;

  SK(0, 0);
  SV(0, 0);
  if (nt > 1) {
    SK(1, 1);
    SV(1, 1);
  }
  if (nt > 2) {
    SK(2, 2);
    SV(2, 2);
  }

  int cur3 = 0;
  for (int j = 0; j < nt; j++) {
    if (j <= nt - 3) {
      asm volatile("s_waitcnt vmcnt(8)" ::: "memory");
    } else if (j == nt - 2) {
      asm volatile("s_waitcnt vmcnt(4)" ::: "memory");
    } else {
      asm volatile("s_waitcnt vmcnt(0)" ::: "memory");
    }
    BARRIER();
    if (j <= jmax) {
      f32x16 st[2];
      st[0] = (f32x16)0.f;
      st[1] = (f32x16)0.f;
      __builtin_amdgcn_s_setprio(1);
#pragma unroll
      for (int sub = 0; sub < 2; sub++) {
        const int row = sub * 32 + q31;
        const int sw = (row & 7) << 4;
#pragma unroll
        for (int ks4 = 0; ks4 < 4; ks4++) {
          bf16x8 kf = *(const bf16x8*)((const char*)Ks[cur3] + row * 128 +
                                       ((ks4 * 32 + h5 * 16) ^ sw));
          st[sub] = __builtin_amdgcn_mfma_f32_32x32x16_bf16(kf, qf[ks4],
                                                            st[sub], 0, 0, 0);
        }
      }
      __builtin_amdgcn_s_setprio(0);
      if (j == jmax) {
        const int t0 = j * 64;
#pragma unroll
        for (int sub = 0; sub < 2; sub++)
#pragma unroll
          for (int r = 0; r < 16; r++) {
            int kv_abs = t0 + sub * 32 + (r & 3) + 8 * (r >> 2) + 4 * h5;
            if (kv_abs > q_abs) st[sub][r] = -1e30f;
          }
      }
      // ---- softmax (log2 domain): tree max, defer-max (THR=8) ----
      float pmax;
      {
        float q0m = -1e30f, q1m = -1e30f;
#pragma unroll
        for (int r = 0; r < 16; r += 4) {
          q0m = fmaxf(q0m, fmaxf(fmaxf(st[0][r], st[0][r + 1]),
                                 fmaxf(st[0][r + 2], st[0][r + 3])));
          q1m = fmaxf(q1m, fmaxf(fmaxf(st[1][r], st[1][r + 1]),
                                 fmaxf(st[1][r + 2], st[1][r + 3])));
        }
        pmax = fmaxf(q0m, q1m);
      }
      pmax = fmaxf(pmax, __shfl_xor(pmax, 32, 64));
      const int defer = __all(pmax - m_reg <= 8.0f);
      if (!defer) {
        float mnew = fmaxf(m_reg, pmax);
        float alpha = exp2_fast(m_reg - mnew);
        m_reg = mnew;
        lrow *= alpha;
#pragma unroll
        for (int r = 0; r < 16; r++) {
          ot0[r] *= alpha;
          ot1[r] *= alpha;
        }
      }
      float rsum = 0.f;
#pragma unroll
      for (int sub = 0; sub < 2; sub++)
#pragma unroll
        for (int r = 0; r < 16; r++) {
          float p = exp2_fast(st[sub][r] - m_reg);
          st[sub][r] = p;
          rsum += p;
        }
      rsum += __shfl_xor(rsum, 32, 64);
      lrow += rsum;
      // ---- pack P to bf16 dwords via v_cvt_pk (T12 primitive) ----
      unsigned int pk[2][8];
#pragma unroll
      for (int sub = 0; sub < 2; sub++)
#pragma unroll
        for (int g = 0; g < 4; g++) {
          pk[sub][2 * g] = cvt_pk_bf16(st[sub][4 * g + 0], st[sub][4 * g + 1]);
          pk[sub][2 * g + 1] =
              cvt_pk_bf16(st[sub][4 * g + 2], st[sub][4 * g + 3]);
        }
      bf16x8 pf[4];
#pragma unroll
      for (int sub = 0; sub < 2; sub++)
#pragma unroll
        for (int s = 0; s < 2; s++) {
          unsigned int a0 = pk[sub][4 * s + 0], a1 = pk[sub][4 * s + 1];
          unsigned int b0 = pk[sub][4 * s + 2], b1 = pk[sub][4 * s + 3];
          unsigned int send0 = h5 ? a0 : b0, send1 = h5 ? a1 : b1;
          unsigned int sh0 = (unsigned int)__shfl_xor((int)send0, 32, 64);
          unsigned int sh1 = (unsigned int)__shfl_xor((int)send1, 32, 64);
          unsigned int ow0 = h5 ? b0 : a0, ow1 = h5 ? b1 : a1;
          u32x4 fu;
          fu[0] = h5 ? sh0 : ow0;
          fu[1] = h5 ? sh1 : ow1;
          fu[2] = h5 ? ow0 : sh0;
          fu[3] = h5 ? ow1 : sh1;
          pf[sub * 2 + s] = *(bf16x8*)&fu;
        }
      __builtin_amdgcn_s_setprio(1);
#pragma unroll
      for (int ks = 0; ks < 4; ks++) {
        const int colb = ks * 32 + h5 * 16;
        {
          const int row = q31;
          bf16x8 vf = *(const bf16x8*)((const char*)Vs[cur3] + row * 128 +
                                       (colb ^ ((row & 7) << 4)));
          ot0 = __builtin_amdgcn_mfma_f32_32x32x16_bf16(vf, pf[ks], ot0, 0, 0, 0);
        }
        {
          const int row = 32 + q31;
          bf16x8 vf = *(const bf16x8*)((const char*)Vs[cur3] + row * 128 +
                                       (colb ^ ((row & 7) << 4)));
          ot1 = __builtin_amdgcn_mfma_f32_32x32x16_bf16(vf, pf[ks], ot1, 0, 0, 0);
        }
      }
      __builtin_amdgcn_s_setprio(0);
    }
    BARRIER();
    if (j + 3 < nt) {
      SK(cur3, j + 3);  // slot j%3 just freed by barrier above
      SV(cur3, j + 3);
    }
    cur3 = (cur3 == 2) ? 0 : cur3 + 1;
  }

  // ---- epilogue: cvt_pk pairs, 8B packed stores ----
  const float rcpl = 1.0f / lrow;
  unsigned short* Orow = O + ((size_t)b * T_ + q_abs) * DM + h * HD;
#pragma unroll
  for (int rg = 0; rg < 4; rg++) {
    uint2 s0;
    s0.x = cvt_pk_bf16(ot0[4 * rg + 0] * rcpl, ot0[4 * rg + 1] * rcpl);
    s0.y = cvt_pk_bf16(ot0[4 * rg + 2] * rcpl, ot0[4 * rg + 3] * rcpl);
    *(uint2*)(Orow + 8 * rg + 4 * h5) = s0;
    uint2 s1;
    s1.x = cvt_pk_bf16(ot1[4 * rg + 0] * rcpl, ot1[4 * rg + 1] * rcpl);
    s1.y = cvt_pk_bf16(ot1[4 * rg + 2] * rcpl, ot1[4 * rg + 3] * rcpl);
    *(uint2*)(Orow + 32 + 8 * rg + 4 * h5) = s1;
  }
#undef SK
#undef SV
}

extern "C" void kernel_launch(void* const* d_in, const int* in_sizes, int n_in,
                              void* d_out, int out_size, void* d_ws,
                              size_t ws_size, hipStream_t stream) {
  const float* x = (const float*)d_in[0];
  const float* cosT = (const float*)d_in[1];
  const float* sinT = (const float*)d_in[2];
  const float* w_qkv = (const float*)d_in[3];
  const float* w_proj = (const float*)d_in[4];
  float* out = (float*)d_out;

  char* ws = (char*)d_ws;
  unsigned short* x16 = (unsigned short*)(ws);                  // 16 MB
  unsigned short* wqkvT = (unsigned short*)(ws + (16 << 20));   // 6 MB
  unsigned short* wprojT = (unsigned short*)(ws + (22 << 20));  // 2 MB
  unsigned short* Qb = (unsigned short*)(ws + (24 << 20));      // 16 MB
  unsigned short* Kb = (unsigned short*)(ws + (40 << 20));      // 16 MB
  unsigned short* VTb = (unsigned short*)(ws + (56 << 20));     // 16 MB
  unsigned short* Ob = x16;  // reuse: x16 dead after gemm_qkv

  prep_kernel<<<6144, 256, 0, stream>>>(x, x16, w_qkv, wqkvT, w_proj, wprojT);
  gemm_qkv<<<1536, 256, 0, stream>>>(x16, wqkvT, cosT, sinT, Qb, Kb, VTb);
  attn_kernel<<<1024, 256, 0, stream>>>(Qb, Kb, VTb, Ob);
  gemm_proj<<<512, 256, 0, stream>>>(Ob, wprojT, out);
}

// Round 17
// 171.307 us; speedup vs baseline: 1.1234x; 1.0079x over previous
//
#include <hip/hip_runtime.h>
#include <cstdint>
#include <cstddef>

typedef __attribute__((ext_vector_type(8))) short bf16x8;
typedef __attribute__((ext_vector_type(4))) float f32x4;
typedef __attribute__((ext_vector_type(16))) float f32x16;
typedef __attribute__((ext_vector_type(4))) unsigned int u32x4;

#define B_ 4
#define T_ 2048
#define DM 1024
#define NH 16
#define HD 64

static __device__ __forceinline__ unsigned short f2bf(float f) {
  union { float f; unsigned int u; } v; v.f = f;
  unsigned int r = v.u + 0x7FFFu + ((v.u >> 16) & 1u);
  return (unsigned short)(r >> 16);
}
static __device__ __forceinline__ float exp2_fast(float x) {
  float r;
  asm volatile("v_exp_f32 %0, %1" : "=v"(r) : "v"(x));
  return r;
}
// packs bf16(a) into lo16, bf16(b) into hi16 (RTNE) — T12 primitive
static __device__ __forceinline__ unsigned int cvt_pk_bf16(float a, float b) {
  unsigned int r;
  asm("v_cvt_pk_bf16_f32 %0, %1, %2" : "=v"(r) : "v"(a), "v"(b));
  return r;
}

static __device__ __forceinline__ void gll16(const void* g, void* l) {
  __builtin_amdgcn_global_load_lds(
      (const __attribute__((address_space(1))) void*)g,
      (__attribute__((address_space(3))) void*)l, 16, 0, 0);
}

#define BARRIER() do { asm volatile("" ::: "memory"); __builtin_amdgcn_s_barrier(); asm volatile("" ::: "memory"); } while (0)
#define WAITV0() asm volatile("s_waitcnt vmcnt(0)" ::: "memory")

// ---------------- merged prep: cast x->bf16 + transpose both weights --------
__global__ __launch_bounds__(256) void prep_kernel(
    const float* __restrict__ x, unsigned short* __restrict__ x16,
    const float* __restrict__ w_qkv, unsigned short* __restrict__ wqkvT,
    const float* __restrict__ w_proj, unsigned short* __restrict__ wprojT) {
  __shared__ unsigned short tile[32][33];
  const int bid = blockIdx.x;
  const int tid = threadIdx.x;
  if (bid < 2048) {
    const int n8 = (B_ * T_ * DM) / 8;  // 1048576
    for (int i = bid * 256 + tid; i < n8; i += 2048 * 256) {
      const float4* p = (const float4*)(x + (size_t)i * 8);
      float4 a = p[0], b = p[1];
      u32x4 o;
      o[0] = cvt_pk_bf16(a.x, a.y);
      o[1] = cvt_pk_bf16(a.z, a.w);
      o[2] = cvt_pk_bf16(b.x, b.y);
      o[3] = cvt_pk_bf16(b.z, b.w);
      *(u32x4*)(x16 + (size_t)i * 8) = o;
    }
    return;
  }
  const float* in;
  unsigned short* out;
  int R, C, bx, by;
  if (bid < 5120) {
    const int b2 = bid - 2048;  // [0,3072)
    in = w_qkv; out = wqkvT; R = 1024; C = 3072;
    bx = b2 % 96; by = b2 / 96;
  } else {
    const int b2 = bid - 5120;  // [0,1024)
    in = w_proj; out = wprojT; R = 1024; C = 1024;
    bx = b2 % 32; by = b2 / 32;
  }
  const int c0 = bx * 32, r0 = by * 32;
  const int tx = tid & 31, ty = tid >> 5;
#pragma unroll
  for (int j = 0; j < 32; j += 8) {
    float v = in[(size_t)(r0 + ty + j) * C + c0 + tx];
    tile[tx][ty + j] = f2bf(v);
  }
  __syncthreads();
#pragma unroll
  for (int j = 0; j < 32; j += 8) {
    out[(size_t)(c0 + ty + j) * R + r0 + tx] = tile[ty + j][tx];
  }
}

// ---------------- GEMM core v1 (m97 single-buffer) --------------------------
#define GEMM_MAIN(As, Bs, Agl, Bgl, acc)                                     \
  {                                                                          \
    const char* gA = (const char*)(Agl) +                                    \
                     (size_t)(m0 + (tid >> 3)) * 2048 +                      \
                     (((tid & 7) ^ ((tid >> 3) & 7)) << 4);                  \
    const char* gB = (const char*)(Bgl) +                                    \
                     (size_t)(n0 + (tid >> 3)) * 2048 +                      \
                     (((tid & 7) ^ ((tid >> 3) & 7)) << 4);                  \
    for (int k0 = 0; k0 < 2048; k0 += 128) {                                 \
      _Pragma("unroll") for (int i = 0; i < 4; i++) {                        \
        gll16(gA + (size_t)i * 65536 + k0, (char*)(As) + i * 4096 + w * 1024);\
        gll16(gB + (size_t)i * 65536 + k0, (char*)(Bs) + i * 4096 + w * 1024);\
      }                                                                      \
      WAITV0();                                                              \
      BARRIER();                                                             \
      _Pragma("unroll") for (int kk = 0; kk < 2; kk++) {                     \
        bf16x8 af[4], bfr[4];                                                \
        const int ko = (kk * 64 + lg * 16) ^ ((lr & 7) << 4);                \
        _Pragma("unroll") for (int mi = 0; mi < 4; mi++)                     \
            af[mi] = *(const bf16x8*)((const char*)(As) +                    \
                                      (wr * 64 + mi * 16 + lr) * 128 + ko);  \
        _Pragma("unroll") for (int ni = 0; ni < 4; ni++)                     \
            bfr[ni] = *(const bf16x8*)((const char*)(Bs) +                   \
                                       (wc * 64 + ni * 16 + lr) * 128 + ko); \
        _Pragma("unroll") for (int mi = 0; mi < 4; mi++)                     \
            _Pragma("unroll") for (int ni = 0; ni < 4; ni++)                 \
                acc[mi][ni] = __builtin_amdgcn_mfma_f32_16x16x32_bf16(       \
                    af[mi], bfr[ni], acc[mi][ni], 0, 0, 0);                  \
      }                                                                      \
      BARRIER();                                                             \
    }                                                                        \
  }

// ---------------- GEMM core v2 (2-phase counted-vmcnt dbuf; proj only) ------
#define GEMM_MAIN2(As, Bs, Agl, Bgl, acc)                                    \
  {                                                                          \
    const char* gA = (const char*)(Agl) +                                    \
                     (size_t)(m0 + (tid >> 3)) * 2048 +                      \
                     (((tid & 7) ^ ((tid >> 3) & 7)) << 4);                  \
    const char* gB = (const char*)(Bgl) +                                    \
                     (size_t)(n0 + (tid >> 3)) * 2048 +                      \
                     (((tid & 7) ^ ((tid >> 3) & 7)) << 4);                  \
    _Pragma("unroll") for (int i = 0; i < 4; i++) {                          \
      gll16(gA + (size_t)i * 65536, (char*)(As) + i * 4096 + w * 1024);      \
      gll16(gB + (size_t)i * 65536, (char*)(Bs) + i * 4096 + w * 1024);      \
    }                                                                        \
    for (int t = 0; t < 16; t++) {                                           \
      const int cur = (t & 1) << 14;                                         \
      if (t < 15) {                                                          \
        const int nxt = ((t + 1) & 1) << 14;                                 \
        const int k0 = (t + 1) * 128;                                        \
        _Pragma("unroll") for (int i = 0; i < 4; i++) {                      \
          gll16(gA + (size_t)i * 65536 + k0,                                 \
                (char*)(As) + nxt + i * 4096 + w * 1024);                    \
          gll16(gB + (size_t)i * 65536 + k0,                                 \
                (char*)(Bs) + nxt + i * 4096 + w * 1024);                    \
        }                                                                    \
        asm volatile("s_waitcnt vmcnt(8)" ::: "memory");                     \
      } else {                                                               \
        asm volatile("s_waitcnt vmcnt(0)" ::: "memory");                     \
      }                                                                      \
      BARRIER();                                                             \
      _Pragma("unroll") for (int kk = 0; kk < 2; kk++) {                     \
        bf16x8 af[4], bfr[4];                                                \
        const int ko = (kk * 64 + lg * 16) ^ ((lr & 7) << 4);                \
        _Pragma("unroll") for (int mi = 0; mi < 4; mi++)                     \
            af[mi] = *(const bf16x8*)((const char*)(As) + cur +              \
                                      (wr * 64 + mi * 16 + lr) * 128 + ko);  \
        _Pragma("unroll") for (int ni = 0; ni < 4; ni++)                     \
            bfr[ni] = *(const bf16x8*)((const char*)(Bs) + cur +             \
                                       (wc * 64 + ni * 16 + lr) * 128 + ko); \
        _Pragma("unroll") for (int mi = 0; mi < 4; mi++)                     \
            _Pragma("unroll") for (int ni = 0; ni < 4; ni++)                 \
                acc[mi][ni] = __builtin_amdgcn_mfma_f32_16x16x32_bf16(       \
                    af[mi], bfr[ni], acc[mi][ni], 0, 0, 0);                  \
      }                                                                      \
      BARRIER();                                                             \
    }                                                                        \
  }

// QKV GEMM + fused RoPE epilogue (cos/sin staged in LDS, XOR-swizzled).
// Outputs Q [bh][t][64] (scaled log2e/8), K [bh][t][64], VT [bh][64][t].
// Grid 1536 1D, XCD-chunked, n-major within XCD.
__global__ __launch_bounds__(256, 4) void gemm_qkv(
    const unsigned short* __restrict__ A, const unsigned short* __restrict__ Bt,
    const float* __restrict__ cosT, const float* __restrict__ sinT,
    unsigned short* __restrict__ Qo, unsigned short* __restrict__ Ko,
    unsigned short* __restrict__ VTo) {
  __shared__ __align__(16) unsigned short As[128 * 64];
  __shared__ __align__(16) unsigned short Bs[128 * 64];
  const int bid = blockIdx.x;
  const int xcd = bid & 7;
  const int cc = bid >> 3;  // [0,192): n-major within XCD
  const int m0 = (xcd * 8 + (cc & 7)) * 128;
  const int n0 = (cc >> 3) * 128;
  const int tid = threadIdx.x;
  const int w = tid >> 6, l = tid & 63;
  const int wr = w >> 1, wc = w & 1;
  const int lr = l & 15, lg = l >> 4;
  f32x4 acc[4][4];
#pragma unroll
  for (int i = 0; i < 4; i++)
#pragma unroll
    for (int j = 0; j < 4; j++) acc[i][j] = (f32x4)0.f;

  GEMM_MAIN(As, Bs, A, Bt, acc)

  // stage this block's cos/sin slice into now-dead As/Bs, XOR-swizzled
  {
    float4* cosL4 = (float4*)As;
    float4* sinL4 = (float4*)Bs;
    const float4* cg = (const float4*)(cosT + (size_t)(m0 & 2047) * 32);
    const float4* sg = (const float4*)(sinT + (size_t)(m0 & 2047) * 32);
#pragma unroll
    for (int i = 0; i < 4; i++) {
      const int c = tid + i * 256;
      const int rw = c >> 3, f4 = c & 7;
      const int slot = rw * 8 + (f4 ^ (((rw >> 2) & 3) << 1));
      cosL4[slot] = cg[c];
      sinL4[slot] = sg[c];
    }
  }
  BARRIER();
  const float* cosL = (const float*)As;
  const float* sinL = (const float*)Bs;

#pragma unroll
  for (int mi = 0; mi < 4; mi++) {
#pragma unroll
    for (int ni = 0; ni < 4; ni++) {
      const int col = n0 + wc * 64 + ni * 16 + lr;
      const int which = col >> 10;
      const int hd = col & 1023;
      const int h = hd >> 6, d = hd & 63;
      const int fi = d >> 1;
      const float sgn = (lr & 1) ? 1.0f : -1.0f;
      const float qsc = (which == 0) ? 0.18033688f : 1.0f;  // log2(e)/8
      float vv[4];
#pragma unroll
      for (int r = 0; r < 4; r++) {
        const int row = m0 + wr * 64 + mi * 16 + lg * 4 + r;
        float v = acc[mi][ni][r];
        if (which < 2) {
          float p = __shfl_xor(v, 1, 64);
          const int fj = fi ^ (((row >> 2) & 3) << 3);
          const int lo = (row & 127) * 32 + fj;
          v = (v * cosL[lo] + sgn * p * sinL[lo]) * qsc;
        }
        vv[r] = v;
      }
      const unsigned int pk0 = cvt_pk_bf16(vv[0], vv[1]);
      const unsigned int pk1 = cvt_pk_bf16(vv[2], vv[3]);
#pragma unroll
      for (int r = 0; r < 4; r++) {
        const int row = m0 + wr * 64 + mi * 16 + lg * 4 + r;
        const int b = row >> 11, tt = row & 2047;
        const unsigned int pk = (r < 2) ? pk0 : pk1;
        const unsigned short bv =
            (unsigned short)((r & 1) ? (pk >> 16) : (pk & 0xFFFFu));
        size_t bh = (size_t)(b * NH + h);
        if (which == 0)
          Qo[(bh * T_ + tt) * HD + d] = bv;
        else if (which == 1)
          Ko[(bh * T_ + tt) * HD + d] = bv;
        else
          VTo[(bh * HD + d) * T_ + tt] = bv;
      }
    }
  }
}

// Proj GEMM: A [8192][1024] bf16 @ Bt [1024][1024] bf16 -> C f32 [8192][1024]
// Grid: 512 1D (= exactly 2 blocks/CU) -> 64KB dbuf LDS is occupancy-neutral.
__global__ __launch_bounds__(256, 2) void gemm_proj(
    const unsigned short* __restrict__ A, const unsigned short* __restrict__ Bt,
    float* __restrict__ C) {
  __shared__ __align__(16) unsigned short As[2 * 8192];
  __shared__ __align__(16) unsigned short Bs[2 * 8192];
  const int bid = blockIdx.x;
  const int xcd = bid & 7;
  const int cc = bid >> 3;  // [0,64)
  const int m0 = (xcd * 8 + cc / 8) * 128;
  const int n0 = (cc % 8) * 128;
  const int tid = threadIdx.x;
  const int w = tid >> 6, l = tid & 63;
  const int wr = w >> 1, wc = w & 1;
  const int lr = l & 15, lg = l >> 4;
  f32x4 acc[4][4];
#pragma unroll
  for (int i = 0; i < 4; i++)
#pragma unroll
    for (int j = 0; j < 4; j++) acc[i][j] = (f32x4)0.f;

  GEMM_MAIN2(As, Bs, A, Bt, acc)

#pragma unroll
  for (int mi = 0; mi < 4; mi++) {
#pragma unroll
    for (int ni = 0; ni < 4; ni++) {
      const int col = n0 + wc * 64 + ni * 16 + lr;
#pragma unroll
      for (int r = 0; r < 4; r++) {
        const int row = m0 + wr * 64 + mi * 16 + lg * 4 + r;
        C[(size_t)row * 1024 + col] = acc[mi][ni][r];
      }
    }
  }
}

// ---------------- Flash attention v6 (R11 best-measured): K 3-buf, V 2-buf,
// 40KB LDS -> 4 blocks/CU; balanced qt mapping assumes 4 co-resident blocks
// (c, c+256, c+512, c+768 sum qt=30 exactly). vmcnt(6/4/0); setprio on MFMA.
__global__ __launch_bounds__(256, 4) void attn_kernel(
    const unsigned short* __restrict__ Q, const unsigned short* __restrict__ K,
    const unsigned short* __restrict__ VT, unsigned short* __restrict__ O) {
  __shared__ __align__(16) unsigned short Ks[3][4096];  // [64 kv][64 d]
  __shared__ __align__(16) unsigned short Vs[2][4096];  // [64 d][64 t]

  const int blk = blockIdx.x;
  const int bh = (blk & 7) * 8 + ((blk >> 3) & 7);
  const int r4 = blk >> 8, g4 = (blk >> 6) & 3;
  const int qt = (r4 == 0) ? (15 - g4)
               : (r4 == 1) ? (8 + g4)
               : (r4 == 2) ? (7 - g4)
                           : g4;
  const int b = bh >> 4, h = bh & 15;
  const int tid = threadIdx.x;
  const int w = tid >> 6, l = tid & 63;
  const int q31 = l & 31, h5 = l >> 5;
  const int q0w = qt * 128 + w * 32;
  const int q_abs = q0w + q31;

  const unsigned short* Qb = Q + (size_t)bh * T_ * HD;
  const char* Kc = (const char*)(K + (size_t)bh * T_ * HD);
  const char* Vc = (const char*)(VT + (size_t)bh * HD * T_);

  const int c0 = (w * 2) * 64 + l;
  const int c1 = (w * 2 + 1) * 64 + l;
  const int r0 = c0 >> 3, r1 = c1 >> 3;
  const int sw0 = ((c0 & 7) * 16) ^ ((r0 & 7) << 4);
  const int sw1 = ((c1 & 7) * 16) ^ ((r1 & 7) << 4);
  const char* pK0 = Kc + r0 * 128 + sw0;
  const char* pK1 = Kc + r1 * 128 + sw1;
  const char* pV0 = Vc + (size_t)r0 * (T_ * 2) + sw0;
  const char* pV1 = Vc + (size_t)r1 * (T_ * 2) + sw1;

#define SK(buf, tile)                                                       \
  do {                                                                      \
    size_t kb = (size_t)(tile) * 8192;                                      \
    gll16(pK0 + kb, (char*)Ks[buf] + (w * 2) * 1024);                       \
    gll16(pK1 + kb, (char*)Ks[buf] + (w * 2 + 1) * 1024);                   \
  } while (0)
#define SV(buf, tile)                                                       \
  do {                                                                      \
    size_t vb = (size_t)(tile) * 128;                                       \
    gll16(pV0 + vb, (char*)Vs[buf] + (w * 2) * 1024);                       \
    gll16(pV1 + vb, (char*)Vs[buf] + (w * 2 + 1) * 1024);                   \
  } while (0)

  bf16x8 qf[4];
#pragma unroll
  for (int ks4 = 0; ks4 < 4; ks4++)
    qf[ks4] = *(const bf16x8*)(Qb + (size_t)q_abs * HD + ks4 * 16 + h5 * 8);

  f32x16 ot0 = (f32x16)0.f, ot1 = (f32x16)0.f;
  float m_reg = -1e30f, lrow = 0.f;

  const int nt = 2 * qt + 2;
  const int jmax = q0w >> 6;

  SK(0, 0);
  SV(0, 0);
  if (nt > 1) {
    SV(1, 1);
    SK(1, 1);
  }
  if (nt > 2) SK(2, 2);

  int kcur = 0;
  for (int j = 0; j < nt; j++) {
    const int vcur = j & 1;
    if (j <= nt - 3) {
      asm volatile("s_waitcnt vmcnt(6)" ::: "memory");
    } else if (j == nt - 2) {
      asm volatile("s_waitcnt vmcnt(4)" ::: "memory");
    } else {
      asm volatile("s_waitcnt vmcnt(0)" ::: "memory");
    }
    BARRIER();
    if (j <= jmax) {
      f32x16 st[2];
      st[0] = (f32x16)0.f;
      st[1] = (f32x16)0.f;
      __builtin_amdgcn_s_setprio(1);
#pragma unroll
      for (int sub = 0; sub < 2; sub++) {
        const int row = sub * 32 + q31;
        const int sw = (row & 7) << 4;
#pragma unroll
        for (int ks4 = 0; ks4 < 4; ks4++) {
          bf16x8 kf = *(const bf16x8*)((const char*)Ks[kcur] + row * 128 +
                                       ((ks4 * 32 + h5 * 16) ^ sw));
          st[sub] = __builtin_amdgcn_mfma_f32_32x32x16_bf16(kf, qf[ks4],
                                                            st[sub], 0, 0, 0);
        }
      }
      __builtin_amdgcn_s_setprio(0);
      if (j == jmax) {
        const int t0 = j * 64;
#pragma unroll
        for (int sub = 0; sub < 2; sub++)
#pragma unroll
          for (int r = 0; r < 16; r++) {
            int kv_abs = t0 + sub * 32 + (r & 3) + 8 * (r >> 2) + 4 * h5;
            if (kv_abs > q_abs) st[sub][r] = -1e30f;
          }
      }
      // ---- softmax (log2 domain): tree max, defer-max (THR=8) ----
      float pmax;
      {
        float q0m = -1e30f, q1m = -1e30f;
#pragma unroll
        for (int r = 0; r < 16; r += 4) {
          q0m = fmaxf(q0m, fmaxf(fmaxf(st[0][r], st[0][r + 1]),
                                 fmaxf(st[0][r + 2], st[0][r + 3])));
          q1m = fmaxf(q1m, fmaxf(fmaxf(st[1][r], st[1][r + 1]),
                                 fmaxf(st[1][r + 2], st[1][r + 3])));
        }
        pmax = fmaxf(q0m, q1m);
      }
      pmax = fmaxf(pmax, __shfl_xor(pmax, 32, 64));
      const int defer = __all(pmax - m_reg <= 8.0f);
      if (!defer) {
        float mnew = fmaxf(m_reg, pmax);
        float alpha = exp2_fast(m_reg - mnew);
        m_reg = mnew;
        lrow *= alpha;
#pragma unroll
        for (int r = 0; r < 16; r++) {
          ot0[r] *= alpha;
          ot1[r] *= alpha;
        }
      }
      float rsum = 0.f;
#pragma unroll
      for (int sub = 0; sub < 2; sub++)
#pragma unroll
        for (int r = 0; r < 16; r++) {
          float p = exp2_fast(st[sub][r] - m_reg);
          st[sub][r] = p;
          rsum += p;
        }
      rsum += __shfl_xor(rsum, 32, 64);
      lrow += rsum;
      // ---- pack P to bf16 dwords via v_cvt_pk (T12 primitive) ----
      unsigned int pk[2][8];
#pragma unroll
      for (int sub = 0; sub < 2; sub++)
#pragma unroll
        for (int g = 0; g < 4; g++) {
          pk[sub][2 * g] = cvt_pk_bf16(st[sub][4 * g + 0], st[sub][4 * g + 1]);
          pk[sub][2 * g + 1] =
              cvt_pk_bf16(st[sub][4 * g + 2], st[sub][4 * g + 3]);
        }
      bf16x8 pf[4];
#pragma unroll
      for (int sub = 0; sub < 2; sub++)
#pragma unroll
        for (int s = 0; s < 2; s++) {
          unsigned int a0 = pk[sub][4 * s + 0], a1 = pk[sub][4 * s + 1];
          unsigned int b0 = pk[sub][4 * s + 2], b1 = pk[sub][4 * s + 3];
          unsigned int send0 = h5 ? a0 : b0, send1 = h5 ? a1 : b1;
          unsigned int sh0 = (unsigned int)__shfl_xor((int)send0, 32, 64);
          unsigned int sh1 = (unsigned int)__shfl_xor((int)send1, 32, 64);
          unsigned int ow0 = h5 ? b0 : a0, ow1 = h5 ? b1 : a1;
          u32x4 fu;
          fu[0] = h5 ? sh0 : ow0;
          fu[1] = h5 ? sh1 : ow1;
          fu[2] = h5 ? ow0 : sh0;
          fu[3] = h5 ? ow1 : sh1;
          pf[sub * 2 + s] = *(bf16x8*)&fu;
        }
      __builtin_amdgcn_s_setprio(1);
#pragma unroll
      for (int ks = 0; ks < 4; ks++) {
        const int colb = ks * 32 + h5 * 16;
        {
          const int row = q31;
          bf16x8 vf = *(const bf16x8*)((const char*)Vs[vcur] + row * 128 +
                                       (colb ^ ((row & 7) << 4)));
          ot0 = __builtin_amdgcn_mfma_f32_32x32x16_bf16(vf, pf[ks], ot0, 0, 0, 0);
        }
        {
          const int row = 32 + q31;
          bf16x8 vf = *(const bf16x8*)((const char*)Vs[vcur] + row * 128 +
                                       (colb ^ ((row & 7) << 4)));
          ot1 = __builtin_amdgcn_mfma_f32_32x32x16_bf16(vf, pf[ks], ot1, 0, 0, 0);
        }
      }
      __builtin_amdgcn_s_setprio(0);
    }
    BARRIER();
    if (j + 2 < nt) SV((j + 2) & 1, j + 2);
    if (j + 3 < nt) SK(kcur, j + 3);
    kcur = (kcur == 2) ? 0 : kcur + 1;
  }

  // ---- epilogue: cvt_pk pairs, 8B packed stores ----
  const float rcpl = 1.0f / lrow;
  unsigned short* Orow = O + ((size_t)b * T_ + q_abs) * DM + h * HD;
#pragma unroll
  for (int rg = 0; rg < 4; rg++) {
    uint2 s0;
    s0.x = cvt_pk_bf16(ot0[4 * rg + 0] * rcpl, ot0[4 * rg + 1] * rcpl);
    s0.y = cvt_pk_bf16(ot0[4 * rg + 2] * rcpl, ot0[4 * rg + 3] * rcpl);
    *(uint2*)(Orow + 8 * rg + 4 * h5) = s0;
    uint2 s1;
    s1.x = cvt_pk_bf16(ot1[4 * rg + 0] * rcpl, ot1[4 * rg + 1] * rcpl);
    s1.y = cvt_pk_bf16(ot1[4 * rg + 2] * rcpl, ot1[4 * rg + 3] * rcpl);
    *(uint2*)(Orow + 32 + 8 * rg + 4 * h5) = s1;
  }
#undef SK
#undef SV
}

extern "C" void kernel_launch(void* const* d_in, const int* in_sizes, int n_in,
                              void* d_out, int out_size, void* d_ws,
                              size_t ws_size, hipStream_t stream) {
  const float* x = (const float*)d_in[0];
  const float* cosT = (const float*)d_in[1];
  const float* sinT = (const float*)d_in[2];
  const float* w_qkv = (const float*)d_in[3];
  const float* w_proj = (const float*)d_in[4];
  float* out = (float*)d_out;

  char* ws = (char*)d_ws;
  unsigned short* x16 = (unsigned short*)(ws);                  // 16 MB
  unsigned short* wqkvT = (unsigned short*)(ws + (16 << 20));   // 6 MB
  unsigned short* wprojT = (unsigned short*)(ws + (22 << 20));  // 2 MB
  unsigned short* Qb = (unsigned short*)(ws + (24 << 20));      // 16 MB
  unsigned short* Kb = (unsigned short*)(ws + (40 << 20));      // 16 MB
  unsigned short* VTb = (unsigned short*)(ws + (56 << 20));     // 16 MB
  unsigned short* Ob = x16;  // reuse: x16 dead after gemm_qkv

  prep_kernel<<<6144, 256, 0, stream>>>(x, x16, w_qkv, wqkvT, w_proj, wprojT);
  gemm_qkv<<<1536, 256, 0, stream>>>(x16, wqkvT, cosT, sinT, Qb, Kb, VTb);
  attn_kernel<<<1024, 256, 0, stream>>>(Qb, Kb, VTb, Ob);
  gemm_proj<<<512, 256, 0, stream>>>(Ob, wprojT, out);
}